// Round 9
// baseline (167.777 us; speedup 1.0000x reference)
//
#include <hip/hip_runtime.h>
#include <math.h>

// critic_attention, round 9: round-8 structure with VALU/latency cuts:
//  (1) A-operand single fp16 (weights stay hi/lo split): D = Ah*Bl + Ah*Bh.
//      Kills per-agent split8 of inputs (64->8 VALU) and 1/3 of phase-A MFMAs.
//  (2) biases folded into MFMA accumulator init (D-row=item, col=lane -> splat).
//  (3) depth-2 prefetch in the fully-unrolled agent loop (static slots).
//
// Fragment conventions (m89-verified, validated rounds 6-8):
//   A-frag: lane holds row (l&15), k = (l>>4)*8 + e
//   B-frag: lane holds col (l&15), k = (l>>4)*8 + e
//   D:      lane holds col (l&15), row = (l>>4)*4 + reg
//
// ws layout (halfs): W0h@0[2][4][4][16][8] W0l@4096 | W2h@8192[4][8][4][16][8]
//   W2l@24576 | W3h@40960 W3l@57344.  Total 73728 halfs = 147456 B.

#define SLOPE 0.01f
#define LOG2E 1.4426950408889634f

typedef _Float16 f16x8 __attribute__((ext_vector_type(8)));
typedef float f32x4 __attribute__((ext_vector_type(4)));

#define MFMA(a, b, c) __builtin_amdgcn_mfma_f32_16x16x32_f16((a), (b), (c), 0, 0, 0)

__device__ __forceinline__ float lrelu(float x) { return fmaxf(x, SLOPE * x); }

__device__ __forceinline__ float fast_tanh(float x) {
    // tanh(x) = 1 - 2/(e^{2x}+1): mul, exp2(trans), add, rcp(trans), fma
    float e = exp2f(x * (2.0f * LOG2E));
    float r = __fdividef(1.0f, e + 1.0f);
    return fmaf(-2.0f, r, 1.0f);
}

__device__ __forceinline__ f16x8 cvt8(const float f[8]) {
    f16x8 r;
#pragma unroll
    for (int e = 0; e < 8; ++e) r[e] = (_Float16)f[e];
    return r;
}

__device__ __forceinline__ void split8(const float f[8], f16x8& hi, f16x8& lo) {
#pragma unroll
    for (int e = 0; e < 8; ++e) {
        _Float16 h = (_Float16)f[e];
        hi[e] = h;
        lo[e] = (_Float16)(f[e] - (float)h);
    }
}

// ---------------- prep: split weights into per-lane fp16 hi/lo fragments ----------------
__global__ __launch_bounds__(256) void pack_weights(
    const float* __restrict__ W0, const float* __restrict__ W2,
    const float* __restrict__ W3, _Float16* __restrict__ ws)
{
    const int g = blockIdx.x * 256 + threadIdx.x;   // fragment group id
    if (g >= 4608) return;

    const float* src;
    int ks, ct, lg, lr, ncol, kmax;
    long hoff, loff;
    if (g < 512) {                       // W0: [2][4][4][16]
        ks = g >> 8; ct = (g >> 6) & 3; lg = (g >> 4) & 3; lr = g & 15;
        src = W0; ncol = 64; kmax = 40;
        hoff = (long)g * 8;  loff = hoff + 4096;
    } else if (g < 2560) {               // W2: [4][8][4][16]
        int gg = g - 512;
        ks = gg >> 9; ct = (gg >> 6) & 7; lg = (gg >> 4) & 3; lr = gg & 15;
        src = W2; ncol = 128; kmax = 128;
        hoff = 8192 + (long)gg * 8; loff = hoff + 16384;
    } else {                             // W3: [4][8][4][16]
        int gg = g - 2560;
        ks = gg >> 9; ct = (gg >> 6) & 7; lg = (gg >> 4) & 3; lr = gg & 15;
        src = W3; ncol = 128; kmax = 128;
        hoff = 40960 + (long)gg * 8; loff = hoff + 16384;
    }

    f16x8 hi, lo;
#pragma unroll
    for (int e = 0; e < 8; ++e) {
        const int k = ks * 32 + lg * 8 + e;
        const float v = (k < kmax) ? src[(long)k * ncol + ct * 16 + lr] : 0.f;
        _Float16 h = (_Float16)v;
        hi[e] = h;
        lo[e] = (_Float16)(v - (float)h);
    }
    *reinterpret_cast<f16x8*>(ws + hoff) = hi;
    *reinterpret_cast<f16x8*>(ws + loff) = lo;
}

__global__ __launch_bounds__(64) void critic_attention_kernel(
    const float* __restrict__ obs, const float* __restrict__ act,
    const float* __restrict__ b0, const float* __restrict__ W1,
    const float* __restrict__ b1v, const float* __restrict__ b2,
    const float* __restrict__ b3, const float* __restrict__ Wc,
    const float* __restrict__ bcv, const _Float16* __restrict__ ws,
    float* __restrict__ out)
{
    __shared__ float xcat[16 * 132];   // one wave's 16 items; stride 132 = 16B-aligned

    const int lane = threadIdx.x;      // 0..63
    const int lr = lane & 15;          // item row (A) / D-col
    const int lg = lane >> 4;          // k-chunk / D-row-group

    const long ibase = (long)blockIdx.x * 16;

    // W0 fragments from ws (stay in regs through the agent loop)
    f16x8 w0h[2][4], w0l[2][4];
#pragma unroll
    for (int ks = 0; ks < 2; ++ks)
#pragma unroll
        for (int ct = 0; ct < 4; ++ct) {
            const long o = (((long)(ks * 4 + ct) * 4 + lg) * 16 + lr) * 8;
            w0h[ks][ct] = *reinterpret_cast<const f16x8*>(ws + o);
            w0l[ks][ct] = *reinterpret_cast<const f16x8*>(ws + 4096 + o);
        }

    float b0c[4], W1sc[4], W1oc[4];
#pragma unroll
    for (int ct = 0; ct < 4; ++ct) {
        b0c[ct]  = b0[ct * 16 + lr];
        W1sc[ct] = W1[ct * 16 + lr];
        W1oc[ct] = W1[64 + ct * 16 + lr];
    }
    const float b1s = b1v[0];

    const float* obase = obs + (ibase + lr) * 512 + lg * 8;   // this lane's item row
    const float* abase = act + (ibase + lr) * 128;            // lg==0 lanes only

    // depth-2 prefetch slots (static indices under full unroll)
    float4 P0[2], P1[2], C0[2], C1[2];
#pragma unroll
    for (int sl = 0; sl < 2; ++sl) {
        P0[sl] = *reinterpret_cast<const float4*>(obase + sl * 32);
        P1[sl] = *reinterpret_cast<const float4*>(obase + sl * 32 + 4);
        C0[sl] = make_float4(0.f, 0.f, 0.f, 0.f);
        C1[sl] = C0[sl];
        if (lg == 0) {
            C0[sl] = *reinterpret_cast<const float4*>(abase + sl * 8);
            C1[sl] = *reinterpret_cast<const float4*>(abase + sl * 8 + 4);
        }
    }

    float a_self[4], s[4], xsum[4][4];
#pragma unroll
    for (int j = 0; j < 4; ++j) {
        s[j] = 0.f;
#pragma unroll
        for (int ct = 0; ct < 4; ++ct) xsum[ct][j] = 0.f;
    }

    // ---------------- agents 0..15, fully unrolled, depth-2 prefetch ----------------
#pragma unroll
    for (int a = 0; a < 16; ++a) {
        const int sl = a & 1;
        float a0f[8] = {P0[sl].x, P0[sl].y, P0[sl].z, P0[sl].w,
                        P1[sl].x, P1[sl].y, P1[sl].z, P1[sl].w};
        float a1f[8] = {C0[sl].x, C0[sl].y, C0[sl].z, C0[sl].w,
                        C1[sl].x, C1[sl].y, C1[sl].z, C1[sl].w};
        f16x8 ah0 = cvt8(a0f);
        f16x8 ah1 = cvt8(a1f);

        if (a + 2 < 16) {   // refill the slot just consumed
            P0[sl] = *reinterpret_cast<const float4*>(obase + (a + 2) * 32);
            P1[sl] = *reinterpret_cast<const float4*>(obase + (a + 2) * 32 + 4);
            if (lg == 0) {
                C0[sl] = *reinterpret_cast<const float4*>(abase + (a + 2) * 8);
                C1[sl] = *reinterpret_cast<const float4*>(abase + (a + 2) * 8 + 4);
            }
        }

        f32x4 acc[4];
#pragma unroll
        for (int ct = 0; ct < 4; ++ct) {
            acc[ct] = (f32x4){b0c[ct], b0c[ct], b0c[ct], b0c[ct]};  // bias folded
            acc[ct] = MFMA(ah0, w0l[0][ct], acc[ct]);
            acc[ct] = MFMA(ah0, w0h[0][ct], acc[ct]);
            acc[ct] = MFMA(ah1, w0l[1][ct], acc[ct]);
            acc[ct] = MFMA(ah1, w0h[1][ct], acc[ct]);
        }

        if (a == 0) {
            // self: lrelu, a_self via 16-lane butterfly, x_self -> LDS
            float xa[4][4], p[4];
#pragma unroll
            for (int j = 0; j < 4; ++j) {
#pragma unroll
                for (int ct = 0; ct < 4; ++ct)
                    xa[ct][j] = lrelu(acc[ct][j]);
                p[j] = xa[0][j] * W1sc[0];
                p[j] = fmaf(xa[1][j], W1sc[1], p[j]);
                p[j] = fmaf(xa[2][j], W1sc[2], p[j]);
                p[j] = fmaf(xa[3][j], W1sc[3], p[j]);
                p[j] += __shfl_xor(p[j], 1, 64);
                p[j] += __shfl_xor(p[j], 2, 64);
                p[j] += __shfl_xor(p[j], 4, 64);
                p[j] += __shfl_xor(p[j], 8, 64);
                a_self[j] = b1s + p[j];
            }
#pragma unroll
            for (int ct = 0; ct < 4; ++ct)
#pragma unroll
                for (int j = 0; j < 4; ++j)
                    xcat[(lg * 4 + j) * 132 + ct * 16 + lr] = xa[ct][j];
        } else {
            float xa[4][4], p[4];
#pragma unroll
            for (int j = 0; j < 4; ++j) {
#pragma unroll
                for (int ct = 0; ct < 4; ++ct)
                    xa[ct][j] = fast_tanh(acc[ct][j]);
                p[j] = xa[0][j] * W1oc[0];
                p[j] = fmaf(xa[1][j], W1oc[1], p[j]);
                p[j] = fmaf(xa[2][j], W1oc[2], p[j]);
                p[j] = fmaf(xa[3][j], W1oc[3], p[j]);
                p[j] += __shfl_xor(p[j], 1, 64);
                p[j] += __shfl_xor(p[j], 2, 64);
                p[j] += __shfl_xor(p[j], 4, 64);
                p[j] += __shfl_xor(p[j], 8, 64);
            }
            // bounded logits -> softmax without max-subtraction
#pragma unroll
            for (int j = 0; j < 4; ++j) {
                const float e = exp2f(lrelu(a_self[j] + p[j]) * LOG2E);
                s[j] += e;
#pragma unroll
                for (int ct = 0; ct < 4; ++ct)
                    xsum[ct][j] = fmaf(e, xa[ct][j], xsum[ct][j]);
            }
        }
    }

    // x_sum -> LDS
#pragma unroll
    for (int j = 0; j < 4; ++j) {
        const float inv = __fdividef(1.f, s[j]);
#pragma unroll
        for (int ct = 0; ct < 4; ++ct)
            xcat[(lg * 4 + j) * 132 + 64 + ct * 16 + lr] = xsum[ct][j] * inv;
    }

    // ---------------- phase B: x_cat[16x128] @ W2 -> x1 -> @ W3 -> x2 -> Wc ----------------
    float b2c[8], b3c[8], Wcc[8];
#pragma unroll
    for (int ct = 0; ct < 8; ++ct) {
        b2c[ct] = b2[ct * 16 + lr];
        b3c[ct] = b3[ct * 16 + lr];
        Wcc[ct] = Wc[ct * 16 + lr];
    }
    const float bcs = bcv[0];

    f32x4 acc2[8];
#pragma unroll
    for (int ct = 0; ct < 8; ++ct)
        acc2[ct] = (f32x4){b2c[ct], b2c[ct], b2c[ct], b2c[ct]};   // bias folded
#pragma unroll
    for (int ks = 0; ks < 4; ++ks) {
        const float* xr = xcat + lr * 132 + ks * 32 + lg * 8;
        float4 r0 = *reinterpret_cast<const float4*>(xr);
        float4 r1 = *reinterpret_cast<const float4*>(xr + 4);
        float av[8] = {r0.x, r0.y, r0.z, r0.w, r1.x, r1.y, r1.z, r1.w};
        f16x8 ah, al;
        split8(av, ah, al);
#pragma unroll
        for (int ct = 0; ct < 8; ++ct) {
            const long gg = ((long)(ks * 8 + ct) * 4 + lg) * 16 + lr;
            f16x8 bh = *reinterpret_cast<const f16x8*>(ws + 8192 + gg * 8);
            f16x8 bl = *reinterpret_cast<const f16x8*>(ws + 24576 + gg * 8);
            acc2[ct] = MFMA(al, bh, acc2[ct]);
            acc2[ct] = MFMA(ah, bl, acc2[ct]);
            acc2[ct] = MFMA(ah, bh, acc2[ct]);
        }
    }
#pragma unroll
    for (int ct = 0; ct < 8; ++ct)
#pragma unroll
        for (int j = 0; j < 4; ++j)
            xcat[(lg * 4 + j) * 132 + ct * 16 + lr] = lrelu(acc2[ct][j]);

#pragma unroll
    for (int ct = 0; ct < 8; ++ct)
        acc2[ct] = (f32x4){b3c[ct], b3c[ct], b3c[ct], b3c[ct]};   // bias folded
#pragma unroll
    for (int ks = 0; ks < 4; ++ks) {
        const float* xr = xcat + lr * 132 + ks * 32 + lg * 8;
        float4 r0 = *reinterpret_cast<const float4*>(xr);
        float4 r1 = *reinterpret_cast<const float4*>(xr + 4);
        float av[8] = {r0.x, r0.y, r0.z, r0.w, r1.x, r1.y, r1.z, r1.w};
        f16x8 ah, al;
        split8(av, ah, al);
#pragma unroll
        for (int ct = 0; ct < 8; ++ct) {
            const long gg = ((long)(ks * 8 + ct) * 4 + lg) * 16 + lr;
            f16x8 bh = *reinterpret_cast<const f16x8*>(ws + 40960 + gg * 8);
            f16x8 bl = *reinterpret_cast<const f16x8*>(ws + 57344 + gg * 8);
            acc2[ct] = MFMA(al, bh, acc2[ct]);
            acc2[ct] = MFMA(ah, bl, acc2[ct]);
            acc2[ct] = MFMA(ah, bh, acc2[ct]);
        }
    }

    // value: per-lane col partials, butterfly over the 16 cols
    float v[4];
#pragma unroll
    for (int j = 0; j < 4; ++j) {
        v[j] = lrelu(acc2[0][j]) * Wcc[0];
#pragma unroll
        for (int ct = 1; ct < 8; ++ct)
            v[j] = fmaf(lrelu(acc2[ct][j]), Wcc[ct], v[j]);
        v[j] += __shfl_xor(v[j], 1, 64);
        v[j] += __shfl_xor(v[j], 2, 64);
        v[j] += __shfl_xor(v[j], 4, 64);
        v[j] += __shfl_xor(v[j], 8, 64);
    }
    if (lr == 0) {
#pragma unroll
        for (int j = 0; j < 4; ++j)
            out[ibase + lg * 4 + j] = v[j] + bcs;
    }
}

extern "C" void kernel_launch(void* const* d_in, const int* in_sizes, int n_in,
                              void* d_out, int out_size, void* d_ws, size_t ws_size,
                              hipStream_t stream) {
    (void)in_sizes; (void)n_in; (void)ws_size; (void)out_size;
    const float* obs = (const float*)d_in[0];
    const float* act = (const float*)d_in[1];
    const float* W0  = (const float*)d_in[2];
    const float* b0  = (const float*)d_in[3];
    const float* W1  = (const float*)d_in[4];
    const float* b1  = (const float*)d_in[5];
    const float* W2  = (const float*)d_in[6];
    const float* b2  = (const float*)d_in[7];
    const float* W3  = (const float*)d_in[8];
    const float* b3  = (const float*)d_in[9];
    const float* Wc  = (const float*)d_in[10];
    const float* bc  = (const float*)d_in[11];
    _Float16* ws = (_Float16*)d_ws;

    pack_weights<<<dim3(18), dim3(256), 0, stream>>>(W0, W2, W3, ws);
    critic_attention_kernel<<<dim3(65536 / 16), dim3(64), 0, stream>>>(
        obs, act, b0, W1, b1, b2, b3, Wc, bc, ws, (float*)d_out);
}